// Round 1
// baseline (259.630 us; speedup 1.0000x reference)
//
#include <hip/hip_runtime.h>

#define B_ 4
#define L_ 4096
#define D_ 1024
#define N_ 64

typedef _Float16 f16;
typedef __attribute__((ext_vector_type(8))) _Float16 half8;
typedef __attribute__((ext_vector_type(4))) float f32x4;

__device__ __forceinline__ float softplus_f(float x) {
    return fmaxf(x, 0.0f) + log1pf(__expf(-fabsf(x)));
}

__device__ __forceinline__ float tanh_f(float x) {
    float xc = fminf(fmaxf(x, -15.0f), 15.0f);
    float e = __expf(2.0f * xc);
    return (e - 1.0f) / (e + 1.0f);
}

// ---------------------------------------------------------------------------
// Prep: WT [192][1024] fp16 (rows 0-127 = Wp cols, 128-191 = Ws cols);
// WoT [1024][64] fp16 (WoT[d][n] = Wo[n][d]).
// ---------------------------------------------------------------------------
__global__ __launch_bounds__(256) void k_prepw(
    const float* __restrict__ Wp, const float* __restrict__ Ws,
    const float* __restrict__ Wo, f16* __restrict__ WT, f16* __restrict__ WoT)
{
    int gid = blockIdx.x * 256 + threadIdx.x;
    if (gid < 24576) {
        int r = gid >> 7, kg = gid & 127;
        const float* src; int ncol, c;
        if (r < 128) { src = Wp; ncol = 128; c = r; }
        else         { src = Ws; ncol = 64;  c = r - 128; }
        f16 h[8];
        #pragma unroll
        for (int j = 0; j < 8; j++)
            h[j] = (f16)src[(size_t)(kg * 8 + j) * ncol + c];
        *(uint4*)&WT[(size_t)r * 1024 + kg * 8] = *(uint4*)h;
    } else {
        int g2 = gid - 24576;                 // < 8192
        int d = g2 >> 3, ng = g2 & 7;
        f16 h[8];
        #pragma unroll
        for (int j = 0; j < 8; j++)
            h[j] = (f16)Wo[(size_t)(ng * 8 + j) * D_ + d];
        *(uint4*)&WoT[(size_t)d * 64 + ng * 8] = *(uint4*)h;
    }
}

// ---------------------------------------------------------------------------
// Fused frontend v2: 512 thr / 8 waves per block = 32 tokens x 192 cols,
// split-K across wave halves (wk = w>>2 picks k-half of each 64-chunk).
// Conv is computed ONCE per chunk into ch[] LDS during staging (no per-wave
// redundancy, conv weights staged to LDS once). Epilogue: wk0 writes raw
// partial sums to sE, wk1 adds its half + bias + activation; then fused
// combine z = dt*Bt*u writes zT/cT n-major fp16.
// ---------------------------------------------------------------------------
__global__ __launch_bounds__(512) void k_frontend(
    const float* __restrict__ x, const float* __restrict__ conv_w,
    const float* __restrict__ conv_b, const f16* __restrict__ WT,
    const float* __restrict__ bp, const float* __restrict__ bs,
    const float* __restrict__ dt_log,
    f16* __restrict__ zT, f16* __restrict__ cT)
{
    __shared__ __align__(16) f16 xh[36 * 72];   // raw x rows t0-4..t0+31
    __shared__ __align__(16) f16 ch[32 * 72];   // conv rows t0..t0+31
    __shared__ __align__(16) float cwS[5 * 1024]; // conv_w[4][1024] + conv_b
    __shared__ float sE[3 * 32 * 68];           // Bt/Ct/u [t][cl], stride 68

    const int tid = threadIdx.x;
    const int w = tid >> 6, lane = tid & 63;
    const int r = lane & 15, q = lane >> 4;
    const int wq = w & 3, wk = w >> 2;          // col-group, k-half
    const int T0 = blockIdx.x * 32;
    const int bb = T0 >> 12;
    const int l0 = T0 & (L_ - 1);
    const int cw0 = wq * 48;

    f32x4 acc[3][2] = {};
    float4 rA, rB;

    // stage conv weights + bias into LDS (once)
    for (int i = tid; i < 1280; i += 512) {
        float4 v = (i < 1024) ? ((const float4*)conv_w)[i]
                              : ((const float4*)conv_b)[i - 1024];
        ((float4*)cwS)[i] = v;
    }

    // --- staging: 576 slots (36 rows x 16 float4); threads 0-63 take two ---
    #define LDX(c0)                                                          \
        {                                                                    \
            {                                                                \
                int row = tid >> 4, g = tid & 15;                            \
                int l = l0 + row - 4;                                        \
                float4 v = make_float4(0.f, 0.f, 0.f, 0.f);                  \
                if (l >= 0)                                                  \
                    v = *(const float4*)&x[((size_t)(bb * L_ + l)) * D_      \
                                           + (c0) + g * 4];                  \
                rA = v;                                                      \
            }                                                                \
            if (tid < 64) {                                                  \
                int row = 32 + (tid >> 4), g = tid & 15;                     \
                int l = l0 + row - 4;                                        \
                rB = *(const float4*)&x[((size_t)(bb * L_ + l)) * D_         \
                                        + (c0) + g * 4];                     \
            }                                                                \
        }

    LDX(0);
    for (int c = 0; c < 16; c++) {
        __syncthreads();   // (a) prev compute done; xh/ch safe; cwS ready
        {
            int row = tid >> 4, g = tid & 15;
            f16 h[4] = {(f16)rA.x, (f16)rA.y, (f16)rA.z, (f16)rA.w};
            *(uint2*)&xh[row * 72 + g * 4] = *(uint2*)h;
            if (tid < 64) {
                int row2 = 32 + (tid >> 4);
                f16 h2[4] = {(f16)rB.x, (f16)rB.y, (f16)rB.z, (f16)rB.w};
                *(uint2*)&xh[row2 * 72 + g * 4] = *(uint2*)h2;
            }
        }
        __syncthreads();   // (b) xh ready
        if (c < 15) LDX((c + 1) * 64);

        // issue A-frag loads early (global L2, independent of LDS)
        const int kl = wk * 32 + q * 8;
        const int kk = c * 64 + kl;
        half8 af0 = *(const half8*)&WT[(size_t)(cw0 + r) * 1024 + kk];
        half8 af1 = *(const half8*)&WT[(size_t)(cw0 + 16 + r) * 1024 + kk];
        half8 af2 = *(const half8*)&WT[(size_t)(cw0 + 32 + r) * 1024 + kk];

        // conv: each thread computes 4 elems of the 32x64 chunk (once!)
        {
            const int row = tid >> 4;          // 0..31
            const int d4 = (tid & 15) * 4;     // dim within chunk
            const int dg = c * 64 + d4;        // global dim
            f32x4 w0 = *(const f32x4*)&cwS[dg];
            f32x4 w1 = *(const f32x4*)&cwS[1024 + dg];
            f32x4 w2 = *(const f32x4*)&cwS[2048 + dg];
            f32x4 w3 = *(const f32x4*)&cwS[3072 + dg];
            f32x4 cb = *(const f32x4*)&cwS[4096 + dg];
            f16 x0[4], x1[4], x2[4], x3[4], ho[4];
            *(uint2*)x0 = *(const uint2*)&xh[(row + 1) * 72 + d4];
            *(uint2*)x1 = *(const uint2*)&xh[(row + 2) * 72 + d4];
            *(uint2*)x2 = *(const uint2*)&xh[(row + 3) * 72 + d4];
            *(uint2*)x3 = *(const uint2*)&xh[(row + 4) * 72 + d4];
            #pragma unroll
            for (int j = 0; j < 4; j++) {
                float s = cb[j];
                s = fmaf(w0[j], (float)x0[j], s);
                s = fmaf(w1[j], (float)x1[j], s);
                s = fmaf(w2[j], (float)x2[j], s);
                s = fmaf(w3[j], (float)x3[j], s);
                ho[j] = (f16)s;
            }
            *(uint2*)&ch[row * 72 + d4] = *(uint2*)ho;
        }
        __syncthreads();   // (c) ch ready

        // MFMA: b-frags straight from LDS, no rebuild
        {
            half8 bc8[2] = {}, br8[2] = {};
            const bool needC = (cw0 < 128);         // wq 0,1,2
            const bool needR = (cw0 + 32 >= 128);   // wq 2,3
            if (needC) {
                #pragma unroll
                for (int nf = 0; nf < 2; nf++)
                    bc8[nf] = *(const half8*)&ch[(nf * 16 + r) * 72 + kl];
            }
            if (needR) {
                #pragma unroll
                for (int nf = 0; nf < 2; nf++)
                    br8[nf] = *(const half8*)&xh[(nf * 16 + r + 4) * 72 + kl];
            }
            #pragma unroll
            for (int mf = 0; mf < 3; mf++) {
                const bool useConv = (cw0 + mf * 16) < 128;
                half8 a8 = (mf == 0) ? af0 : ((mf == 1) ? af1 : af2);
                #pragma unroll
                for (int nf = 0; nf < 2; nf++)
                    acc[mf][nf] = __builtin_amdgcn_mfma_f32_16x16x32_f16(
                        a8, useConv ? bc8[nf] : br8[nf], acc[mf][nf], 0, 0, 0);
            }
        }
    }

    // --- epilogue: split-K reduce via sE, then bias + activation ---
    float* sB = sE;
    float* sC = sE + 32 * 68;
    float* sU = sE + 2 * 32 * 68;
    if (wk == 0) {
        #pragma unroll
        for (int mf = 0; mf < 3; mf++) {
            const int cb4 = cw0 + mf * 16 + q * 4;
            const int seg = cb4 >> 6;
            const int cl = cb4 & 63;
            float* dst = (seg == 0) ? sB : (seg == 1 ? sC : sU);
            #pragma unroll
            for (int nf = 0; nf < 2; nf++) {
                const int t = nf * 16 + r;
                float4 vv = {acc[mf][nf][0], acc[mf][nf][1],
                             acc[mf][nf][2], acc[mf][nf][3]};
                *(float4*)&dst[t * 68 + cl] = vv;
            }
        }
    }
    __syncthreads();
    if (wk == 1) {
        #pragma unroll
        for (int mf = 0; mf < 3; mf++) {
            const int cb4 = cw0 + mf * 16 + q * 4;
            const int seg = cb4 >> 6;
            const int cl = cb4 & 63;
            const float4 bb4 = (seg == 2) ? *(const float4*)&bs[cl]
                                          : *(const float4*)&bp[cb4];
            float* dst = (seg == 0) ? sB : (seg == 1 ? sC : sU);
            #pragma unroll
            for (int nf = 0; nf < 2; nf++) {
                const int t = nf * 16 + r;
                float4 p = *(float4*)&dst[t * 68 + cl];
                float v0 = acc[mf][nf][0] + p.x + bb4.x;
                float v1 = acc[mf][nf][1] + p.y + bb4.y;
                float v2 = acc[mf][nf][2] + p.z + bb4.z;
                float v3 = acc[mf][nf][3] + p.w + bb4.w;
                if (seg == 0) {
                    v0 = softplus_f(v0); v1 = softplus_f(v1);
                    v2 = softplus_f(v2); v3 = softplus_f(v3);
                } else if (seg == 1) {
                    v0 = tanh_f(v0); v1 = tanh_f(v1);
                    v2 = tanh_f(v2); v3 = tanh_f(v3);
                }
                float4 vv = {v0, v1, v2, v3};
                *(float4*)&dst[t * 68 + cl] = vv;
            }
        }
    }
    __syncthreads();

    // --- fused combine: z = dt[n]*Bt*u, store zT/cT n-major ---
    {
        const int n = tid >> 3, tg = tid & 7;
        const float dtv = softplus_f(dt_log[n]);
        f16 hz[4], hc[4];
        #pragma unroll
        for (int j = 0; j < 4; j++) {
            const int t = tg * 4 + j;
            hz[j] = (f16)(dtv * sB[t * 68 + n] * sU[t * 68 + n]);
            hc[j] = (f16)sC[t * 68 + n];
        }
        size_t o = ((size_t)(bb * N_ + n)) * L_ + l0 + tg * 4;
        *(uint2*)&zT[o] = *(uint2*)hz;
        *(uint2*)&cT[o] = *(uint2*)hc;
    }
    #undef LDX
}

// ---------------------------------------------------------------------------
// Scan: one wave per (b,n) chain; exact affine chunk-stitched scan.
// ---------------------------------------------------------------------------
__global__ __launch_bounds__(64) void k_scan(
    const f16* __restrict__ zT, const f16* __restrict__ cT,
    const float* __restrict__ A_log, const float* __restrict__ dt_log,
    f16* __restrict__ yH)
{
    __shared__ float zs[L_];
    __shared__ float cs[L_];
    const int bn = blockIdx.x;
    const int n = bn & (N_ - 1);
    const int lane = threadIdx.x;
    const f16* zp = zT + (size_t)bn * L_;
    const f16* cp = cT + (size_t)bn * L_;

    for (int it = 0; it < 8; it++) {
        int i = lane * 8 + it * 512;
        uint4 rz = *(const uint4*)(zp + i);
        uint4 rc = *(const uint4*)(cp + i);
        const f16* hz = (const f16*)&rz;
        const f16* hc = (const f16*)&rc;
        #pragma unroll
        for (int k = 0; k < 8; k++) {
            zs[i + k] = (float)hz[k];
            cs[i + k] = (float)hc[k];
        }
    }
    __syncthreads();

    float dtv = softplus_f(dt_log[n]);
    float Av = -softplus_f(A_log[n]);
    float dec = fmaf(dtv, Av, 1.0f);

    float s = 0.0f;
    const int base = lane * 64;
    #pragma unroll
    for (int j = 0; j < 64; j++) s = fmaf(dec, s, zs[base + j]);

    float d2 = dec * dec, d4 = d2 * d2, d8 = d4 * d4;
    float d16 = d8 * d8, d32 = d16 * d16, d64 = d32 * d32;

    float Ag = d64, Bg = s;
    #pragma unroll
    for (int off = 1; off < 64; off <<= 1) {
        float Ap = __shfl_up(Ag, off);
        float Bp = __shfl_up(Bg, off);
        if (lane >= off) { Bg = fmaf(Ag, Bp, Bg); Ag *= Ap; }
    }
    float carry = __shfl_up(Bg, 1);
    if (lane == 0) carry = 0.0f;

    float st = carry;
    #pragma unroll
    for (int j = 0; j < 64; j++) {
        st = fmaf(dec, st, zs[base + j]);
        zs[base + j] = cs[base + j] * st;
    }
    __syncthreads();
    f16* yp = yH + (size_t)bn * L_;
    for (int i = lane * 8; i < L_; i += 512) {
        f16 h[8];
        #pragma unroll
        for (int k = 0; k < 8; k++) h[k] = (f16)zs[i + k];
        *(uint4*)&yp[i] = *(uint4*)h;
    }
}

// ---------------------------------------------------------------------------
// Out GEMM: out[t][d] = y[t][:] @ Wo[:,d] + bo.  A = WoT (m=d), B = y (n=tok)
// -> D rows are d -> float4 coalesced stores.  Block 256 thr: 64 tok x 128 d,
// wave = 32 d x 64 tok.  Grid (256, 8) = 2048 blocks = 8/CU.
// ---------------------------------------------------------------------------
__global__ __launch_bounds__(256) void k_out(
    const f16* __restrict__ yH, const f16* __restrict__ WoT,
    const float* __restrict__ bo, float* __restrict__ out)
{
    __shared__ __align__(16) f16 ys[64 * 72];
    const int tid = threadIdx.x;
    const int w = tid >> 6, lane = tid & 63;
    const int r = lane & 15, q = lane >> 4;
    const int T0 = blockIdx.x * 64;
    const int bb = T0 >> 12, l0 = T0 & (L_ - 1);
    const int dw = blockIdx.y * 128 + w * 32;

    // stage y transpose: [n-major global] -> ys[t][n]
    {
        const int n = tid & 63, tg = tid >> 6;
        #pragma unroll
        for (int h2 = 0; h2 < 2; h2++) {
            uint4 v = *(const uint4*)&yH[((size_t)(bb * N_ + n)) * L_ + l0 + tg * 16 + h2 * 8];
            const f16* hh = (const f16*)&v;
            #pragma unroll
            for (int j = 0; j < 8; j++)
                ys[(tg * 16 + h2 * 8 + j) * 72 + n] = hh[j];
        }
    }
    __syncthreads();

    f32x4 acc[2][4] = {};
    #pragma unroll
    for (int ks = 0; ks < 2; ks++) {
        const int kk = ks * 32 + q * 8;
        half8 af[2];
        #pragma unroll
        for (int mf = 0; mf < 2; mf++)
            af[mf] = *(const half8*)&WoT[(size_t)(dw + mf * 16 + r) * 64 + kk];
        #pragma unroll
        for (int nf = 0; nf < 4; nf++) {
            half8 bf = *(const half8*)&ys[(nf * 16 + r) * 72 + kk];
            #pragma unroll
            for (int mf = 0; mf < 2; mf++)
                acc[mf][nf] = __builtin_amdgcn_mfma_f32_16x16x32_f16(
                    af[mf], bf, acc[mf][nf], 0, 0, 0);
        }
    }

    #pragma unroll
    for (int mf = 0; mf < 2; mf++) {
        const int d = dw + mf * 16 + q * 4;
        const float4 bb4 = *(const float4*)&bo[d];
        #pragma unroll
        for (int nf = 0; nf < 4; nf++) {
            const int t = T0 + nf * 16 + r;
            float4 o = {acc[mf][nf][0] + bb4.x, acc[mf][nf][1] + bb4.y,
                        acc[mf][nf][2] + bb4.z, acc[mf][nf][3] + bb4.w};
            *(float4*)&out[(size_t)t * D_ + d] = o;
        }
    }
}

// ---------------------------------------------------------------------------
extern "C" void kernel_launch(void* const* d_in, const int* in_sizes, int n_in,
                              void* d_out, int out_size, void* d_ws, size_t ws_size,
                              hipStream_t stream) {
    const float* x      = (const float*)d_in[0];
    const float* conv_w = (const float*)d_in[1];
    const float* conv_b = (const float*)d_in[2];
    const float* Wp     = (const float*)d_in[3];
    const float* bp     = (const float*)d_in[4];
    const float* Ws     = (const float*)d_in[5];
    const float* bs     = (const float*)d_in[6];
    const float* A_log  = (const float*)d_in[7];
    const float* dt_log = (const float*)d_in[8];
    const float* Wo     = (const float*)d_in[9];
    const float* bo     = (const float*)d_in[10];
    float* out = (float*)d_out;

    char* wsp = (char*)d_ws;
    f16* WT  = (f16*)wsp;                     // 384 KB
    f16* WoT = (f16*)(wsp + 393216);          // 128 KB
    f16* zT  = (f16*)(wsp + 524288);          // 2 MB [B,N,L]
    f16* cT  = (f16*)(wsp + 2621440);         // 2 MB
    f16* yH  = (f16*)(wsp + 4718592);         // 2 MB

    k_prepw<<<dim3(128), dim3(256), 0, stream>>>(Wp, Ws, Wo, WT, WoT);
    k_frontend<<<dim3(B_ * L_ / 32), dim3(512), 0, stream>>>(
        x, conv_w, conv_b, WT, bp, bs, dt_log, zT, cT);
    k_scan<<<dim3(B_ * N_), dim3(64), 0, stream>>>(zT, cT, A_log, dt_log, yH);
    k_out<<<dim3(B_ * L_ / 64, D_ / 128), dim3(256), 0, stream>>>(yH, WoT, bo, out);
}

// Round 2
// 241.702 us; speedup vs baseline: 1.0742x; 1.0742x over previous
//
#include <hip/hip_runtime.h>

#define B_ 4
#define L_ 4096
#define D_ 1024
#define N_ 64

typedef _Float16 f16;
typedef __attribute__((ext_vector_type(8))) _Float16 half8;
typedef __attribute__((ext_vector_type(4))) float f32x4;

__device__ __forceinline__ float softplus_f(float x) {
    return fmaxf(x, 0.0f) + log1pf(__expf(-fabsf(x)));
}

__device__ __forceinline__ float tanh_f(float x) {
    float xc = fminf(fmaxf(x, -15.0f), 15.0f);
    float e = __expf(2.0f * xc);
    return (e - 1.0f) / (e + 1.0f);
}

// ---------------------------------------------------------------------------
// Prep: WT2 [576][1024] f16:
//   rows k*128+c (k=0..3, c=0..127): Wk'[c][d] = conv_w[k][d] * Wp[d][c]
//   rows 512+c  (c=0..63):           Ws[d][c]
// WoT [1024][64] f16 (WoT[d][n] = Wo[n][d]).
// bpE [128] f32: bp[c] + sum_d conv_b[d]*Wp[d][c]  (conv bias folded).
// Grid: 321 blocks x 256 (branches are block-uniform).
// ---------------------------------------------------------------------------
__global__ __launch_bounds__(256) void k_prepw(
    const float* __restrict__ conv_w, const float* __restrict__ conv_b,
    const float* __restrict__ Wp, const float* __restrict__ bp,
    const float* __restrict__ Ws, const float* __restrict__ Wo,
    f16* __restrict__ WT2, f16* __restrict__ WoT, float* __restrict__ bpE)
{
    int gid = blockIdx.x * 256 + threadIdx.x;
    if (gid < 73728) {                        // 576 rows x 16 groups of 8
        int row = gid >> 7, kg = gid & 127;
        f16 h[8];
        if (row < 512) {
            int k = row >> 7, cc = row & 127;
            #pragma unroll
            for (int j = 0; j < 8; j++) {
                int d = kg * 8 + j;
                h[j] = (f16)(conv_w[k * D_ + d] * Wp[(size_t)d * 128 + cc]);
            }
        } else {
            int cc = row - 512;
            #pragma unroll
            for (int j = 0; j < 8; j++)
                h[j] = (f16)Ws[(size_t)(kg * 8 + j) * 64 + cc];
        }
        *(uint4*)&WT2[(size_t)row * 1024 + kg * 8] = *(uint4*)h;
    } else if (gid < 81920) {                 // WoT transpose
        int g2 = gid - 73728;
        int d = g2 >> 3, ng = g2 & 7;
        f16 h[8];
        #pragma unroll
        for (int j = 0; j < 8; j++)
            h[j] = (f16)Wo[(size_t)(ng * 8 + j) * D_ + d];
        *(uint4*)&WoT[(size_t)d * 64 + ng * 8] = *(uint4*)h;
    } else {                                  // bpE: 2 threads per col
        int idx = gid - 81920;                // 0..255
        int cc = idx >> 1, hh = idx & 1;
        float s = 0.0f;
        #pragma unroll 4
        for (int d = hh * 512; d < hh * 512 + 512; d++)
            s = fmaf(conv_b[d], Wp[(size_t)d * 128 + cc], s);
        s += __shfl_xor(s, 1);
        if (hh == 0) bpE[cc] = bp[cc] + s;
    }
}

// ---------------------------------------------------------------------------
// Fused frontend v3: 256 thr / 4 waves, 32 tokens/block (proven structure).
// Conv folded into the GEMM: proj[t] = sum_k x[t-3+k] @ Wk'  -> 4-shift MFMA
// where shift-k B-frag = LDS row (tok+1+k); u shares the k=3 row.  No conv
// VALU, no conv_w loads, no ch buffer.  Wave w: proj cols w*32..+31 (2 frags
// x 4 shifts) + u cols w*16..+15 (1 frag) -> 18 MFMA/ks, perfectly balanced.
// Epilogue: bias(bpE/bs) + activation -> sE; combine z = dt*Bt*u -> zT/cT.
// ---------------------------------------------------------------------------
__global__ __launch_bounds__(256) void k_frontend(
    const float* __restrict__ x, const f16* __restrict__ WT2,
    const float* __restrict__ bpE, const float* __restrict__ bs,
    const float* __restrict__ dt_log,
    f16* __restrict__ zT, f16* __restrict__ cT)
{
    __shared__ __align__(16) f16 xh[36 * 72];   // rows t0-4..t0+31, stride 72
    __shared__ float sE[3 * 32 * 68];           // Bt/Ct/u [t][cl], stride 68

    const int tid = threadIdx.x;
    const int w = tid >> 6, lane = tid & 63;
    const int r = lane & 15, q = lane >> 4;
    const int T0 = blockIdx.x * 32;
    const int bb = T0 >> 12;
    const int l0 = T0 & (L_ - 1);
    const int cp0 = w * 32;                     // proj col base (0..96)
    const int cu0 = w * 16;                     // u col base (0..48)

    f32x4 accp[2][2] = {};                      // [mf][nf]
    f32x4 accu[2] = {};                         // [nf]
    float4 rA[3];

    // --- staging: 36 rows x 16 float4, register prefetch (proven codegen) ---
    #define LDX(c0)                                                          \
        {                                                                    \
            _Pragma("unroll")                                                \
            for (int s = 0; s < 3; s++) {                                    \
                int idx = tid + 256 * s;                                     \
                float4 v = make_float4(0.f, 0.f, 0.f, 0.f);                  \
                if (idx < 576) {                                             \
                    int row = idx >> 4, g = idx & 15;                        \
                    int l = l0 + row - 4;                                    \
                    if (l >= 0)                                              \
                        v = *(const float4*)&x[((size_t)(bb * L_ + l)) * D_  \
                                               + (c0) + g * 4];              \
                }                                                            \
                rA[s] = v;                                                   \
            }                                                                \
        }

    LDX(0);
    for (int c = 0; c < 16; c++) {
        __syncthreads();
        #pragma unroll
        for (int s = 0; s < 3; s++) {
            int idx = tid + 256 * s;
            if (idx < 576) {
                int row = idx >> 4, g = idx & 15;
                f16 h[4] = {(f16)rA[s].x, (f16)rA[s].y, (f16)rA[s].z, (f16)rA[s].w};
                *(uint2*)&xh[row * 72 + g * 4] = *(uint2*)h;
            }
        }
        __syncthreads();
        if (c < 15) LDX((c + 1) * 64);

        const int k0 = c * 64;
        #pragma unroll
        for (int ks = 0; ks < 2; ks++) {
            const int kl = ks * 32 + q * 8;     // k within chunk
            const int kk = k0 + kl;             // global k

            half8 ap[2][4];                     // [mf][shift]
            #pragma unroll
            for (int mf = 0; mf < 2; mf++)
                #pragma unroll
                for (int k = 0; k < 4; k++)
                    ap[mf][k] = *(const half8*)&WT2[
                        (size_t)(k * 128 + cp0 + mf * 16 + r) * 1024 + kk];
            half8 au = *(const half8*)&WT2[(size_t)(512 + cu0 + r) * 1024 + kk];

            #pragma unroll
            for (int nf = 0; nf < 2; nf++) {
                const int rb = nf * 16 + r;
                half8 b0 = *(const half8*)&xh[(rb + 1) * 72 + kl];
                half8 b1 = *(const half8*)&xh[(rb + 2) * 72 + kl];
                half8 b2 = *(const half8*)&xh[(rb + 3) * 72 + kl];
                half8 b3 = *(const half8*)&xh[(rb + 4) * 72 + kl];
                // interleave k-steps across the two independent accumulators
                accp[0][nf] = __builtin_amdgcn_mfma_f32_16x16x32_f16(
                    ap[0][0], b0, accp[0][nf], 0, 0, 0);
                accp[1][nf] = __builtin_amdgcn_mfma_f32_16x16x32_f16(
                    ap[1][0], b0, accp[1][nf], 0, 0, 0);
                accp[0][nf] = __builtin_amdgcn_mfma_f32_16x16x32_f16(
                    ap[0][1], b1, accp[0][nf], 0, 0, 0);
                accp[1][nf] = __builtin_amdgcn_mfma_f32_16x16x32_f16(
                    ap[1][1], b1, accp[1][nf], 0, 0, 0);
                accp[0][nf] = __builtin_amdgcn_mfma_f32_16x16x32_f16(
                    ap[0][2], b2, accp[0][nf], 0, 0, 0);
                accp[1][nf] = __builtin_amdgcn_mfma_f32_16x16x32_f16(
                    ap[1][2], b2, accp[1][nf], 0, 0, 0);
                accp[0][nf] = __builtin_amdgcn_mfma_f32_16x16x32_f16(
                    ap[0][3], b3, accp[0][nf], 0, 0, 0);
                accp[1][nf] = __builtin_amdgcn_mfma_f32_16x16x32_f16(
                    ap[1][3], b3, accp[1][nf], 0, 0, 0);
                accu[nf] = __builtin_amdgcn_mfma_f32_16x16x32_f16(
                    au, b3, accu[nf], 0, 0, 0);
            }
        }
    }

    // --- epilogue: bias + activation -> sE ---
    float* sB = sE;
    float* sC = sE + 32 * 68;
    float* sU = sE + 2 * 32 * 68;
    __syncthreads();
    #pragma unroll
    for (int mf = 0; mf < 2; mf++) {
        const int cb4 = cp0 + mf * 16 + q * 4;  // proj col, 0..127
        const int seg = cb4 >> 6;               // 0=Bt 1=Ct (frag-uniform)
        const int cl = cb4 & 63;
        const float4 bb4 = *(const float4*)&bpE[cb4];
        float* dst = seg ? sC : sB;
        #pragma unroll
        for (int nf = 0; nf < 2; nf++) {
            const int t = nf * 16 + r;
            float v0 = accp[mf][nf][0] + bb4.x;
            float v1 = accp[mf][nf][1] + bb4.y;
            float v2 = accp[mf][nf][2] + bb4.z;
            float v3 = accp[mf][nf][3] + bb4.w;
            if (seg == 0) {
                v0 = softplus_f(v0); v1 = softplus_f(v1);
                v2 = softplus_f(v2); v3 = softplus_f(v3);
            } else {
                v0 = tanh_f(v0); v1 = tanh_f(v1);
                v2 = tanh_f(v2); v3 = tanh_f(v3);
            }
            float4 vv = {v0, v1, v2, v3};
            *(float4*)&dst[t * 68 + cl] = vv;
        }
    }
    {
        const int cu = cu0 + q * 4;             // u col, 0..63
        const float4 bb4 = *(const float4*)&bs[cu];
        #pragma unroll
        for (int nf = 0; nf < 2; nf++) {
            const int t = nf * 16 + r;
            float4 vv = {accu[nf][0] + bb4.x, accu[nf][1] + bb4.y,
                         accu[nf][2] + bb4.z, accu[nf][3] + bb4.w};
            *(float4*)&sU[t * 68 + cu] = vv;
        }
    }
    __syncthreads();

    // --- fused combine: z = dt[n]*Bt*u, store zT/cT n-major ---
    {
        const int n = tid >> 2, tg = tid & 3;
        const float dtv = softplus_f(dt_log[n]);
        f16 hz[8], hc[8];
        #pragma unroll
        for (int j = 0; j < 8; j++) {
            const int t = tg * 8 + j;
            hz[j] = (f16)(dtv * sB[t * 68 + n] * sU[t * 68 + n]);
            hc[j] = (f16)sC[t * 68 + n];
        }
        size_t o = ((size_t)(bb * N_ + n)) * L_ + l0 + tg * 8;
        *(uint4*)&zT[o] = *(uint4*)hz;
        *(uint4*)&cT[o] = *(uint4*)hc;
    }
    #undef LDX
}

// ---------------------------------------------------------------------------
// Scan: one wave per (b,n) chain; exact affine chunk-stitched scan.
// ---------------------------------------------------------------------------
__global__ __launch_bounds__(64) void k_scan(
    const f16* __restrict__ zT, const f16* __restrict__ cT,
    const float* __restrict__ A_log, const float* __restrict__ dt_log,
    f16* __restrict__ yH)
{
    __shared__ float zs[L_];
    __shared__ float cs[L_];
    const int bn = blockIdx.x;
    const int n = bn & (N_ - 1);
    const int lane = threadIdx.x;
    const f16* zp = zT + (size_t)bn * L_;
    const f16* cp = cT + (size_t)bn * L_;

    for (int it = 0; it < 8; it++) {
        int i = lane * 8 + it * 512;
        uint4 rz = *(const uint4*)(zp + i);
        uint4 rc = *(const uint4*)(cp + i);
        const f16* hz = (const f16*)&rz;
        const f16* hc = (const f16*)&rc;
        #pragma unroll
        for (int k = 0; k < 8; k++) {
            zs[i + k] = (float)hz[k];
            cs[i + k] = (float)hc[k];
        }
    }
    __syncthreads();

    float dtv = softplus_f(dt_log[n]);
    float Av = -softplus_f(A_log[n]);
    float dec = fmaf(dtv, Av, 1.0f);

    float s = 0.0f;
    const int base = lane * 64;
    #pragma unroll
    for (int j = 0; j < 64; j++) s = fmaf(dec, s, zs[base + j]);

    float d2 = dec * dec, d4 = d2 * d2, d8 = d4 * d4;
    float d16 = d8 * d8, d32 = d16 * d16, d64 = d32 * d32;

    float Ag = d64, Bg = s;
    #pragma unroll
    for (int off = 1; off < 64; off <<= 1) {
        float Ap = __shfl_up(Ag, off);
        float Bp = __shfl_up(Bg, off);
        if (lane >= off) { Bg = fmaf(Ag, Bp, Bg); Ag *= Ap; }
    }
    float carry = __shfl_up(Bg, 1);
    if (lane == 0) carry = 0.0f;

    float st = carry;
    #pragma unroll
    for (int j = 0; j < 64; j++) {
        st = fmaf(dec, st, zs[base + j]);
        zs[base + j] = cs[base + j] * st;
    }
    __syncthreads();
    f16* yp = yH + (size_t)bn * L_;
    for (int i = lane * 8; i < L_; i += 512) {
        f16 h[8];
        #pragma unroll
        for (int k = 0; k < 8; k++) h[k] = (f16)zs[i + k];
        *(uint4*)&yp[i] = *(uint4*)h;
    }
}

// ---------------------------------------------------------------------------
// Out GEMM: out[t][d] = y[t][:] @ Wo[:,d] + bo.  A = WoT (m=d), B = y (n=tok)
// -> D rows are d -> float4 coalesced stores.  Block 256 thr: 64 tok x 128 d,
// wave = 32 d x 64 tok.  Grid (256, 8) = 2048 blocks = 8/CU.
// ---------------------------------------------------------------------------
__global__ __launch_bounds__(256) void k_out(
    const f16* __restrict__ yH, const f16* __restrict__ WoT,
    const float* __restrict__ bo, float* __restrict__ out)
{
    __shared__ __align__(16) f16 ys[64 * 72];
    const int tid = threadIdx.x;
    const int w = tid >> 6, lane = tid & 63;
    const int r = lane & 15, q = lane >> 4;
    const int T0 = blockIdx.x * 64;
    const int bb = T0 >> 12, l0 = T0 & (L_ - 1);
    const int dw = blockIdx.y * 128 + w * 32;

    // stage y transpose: [n-major global] -> ys[t][n]
    {
        const int n = tid & 63, tg = tid >> 6;
        #pragma unroll
        for (int h2 = 0; h2 < 2; h2++) {
            uint4 v = *(const uint4*)&yH[((size_t)(bb * N_ + n)) * L_ + l0 + tg * 16 + h2 * 8];
            const f16* hh = (const f16*)&v;
            #pragma unroll
            for (int j = 0; j < 8; j++)
                ys[(tg * 16 + h2 * 8 + j) * 72 + n] = hh[j];
        }
    }
    __syncthreads();

    f32x4 acc[2][4] = {};
    #pragma unroll
    for (int ks = 0; ks < 2; ks++) {
        const int kk = ks * 32 + q * 8;
        half8 af[2];
        #pragma unroll
        for (int mf = 0; mf < 2; mf++)
            af[mf] = *(const half8*)&WoT[(size_t)(dw + mf * 16 + r) * 64 + kk];
        #pragma unroll
        for (int nf = 0; nf < 4; nf++) {
            half8 bf = *(const half8*)&ys[(nf * 16 + r) * 72 + kk];
            #pragma unroll
            for (int mf = 0; mf < 2; mf++)
                acc[mf][nf] = __builtin_amdgcn_mfma_f32_16x16x32_f16(
                    af[mf], bf, acc[mf][nf], 0, 0, 0);
        }
    }

    #pragma unroll
    for (int mf = 0; mf < 2; mf++) {
        const int d = dw + mf * 16 + q * 4;
        const float4 bb4 = *(const float4*)&bo[d];
        #pragma unroll
        for (int nf = 0; nf < 4; nf++) {
            const int t = T0 + nf * 16 + r;
            float4 o = {acc[mf][nf][0] + bb4.x, acc[mf][nf][1] + bb4.y,
                        acc[mf][nf][2] + bb4.z, acc[mf][nf][3] + bb4.w};
            *(float4*)&out[(size_t)t * D_ + d] = o;
        }
    }
}

// ---------------------------------------------------------------------------
extern "C" void kernel_launch(void* const* d_in, const int* in_sizes, int n_in,
                              void* d_out, int out_size, void* d_ws, size_t ws_size,
                              hipStream_t stream) {
    const float* x      = (const float*)d_in[0];
    const float* conv_w = (const float*)d_in[1];
    const float* conv_b = (const float*)d_in[2];
    const float* Wp     = (const float*)d_in[3];
    const float* bp     = (const float*)d_in[4];
    const float* Ws     = (const float*)d_in[5];
    const float* bs     = (const float*)d_in[6];
    const float* A_log  = (const float*)d_in[7];
    const float* dt_log = (const float*)d_in[8];
    const float* Wo     = (const float*)d_in[9];
    const float* bo     = (const float*)d_in[10];
    float* out = (float*)d_out;

    char* wsp = (char*)d_ws;
    f16* WT2   = (f16*)wsp;                     // 1,179,648 B
    f16* WoT   = (f16*)(wsp + 1179648);         // 131,072 B
    float* bpE = (float*)(wsp + 1310720);       // 512 B
    f16* zT    = (f16*)(wsp + 1311744);         // 2 MB [B,N,L]
    f16* cT    = (f16*)(wsp + 3408896);         // 2 MB
    f16* yH    = (f16*)(wsp + 5506048);         // 2 MB

    k_prepw<<<dim3(321), dim3(256), 0, stream>>>(
        conv_w, conv_b, Wp, bp, Ws, Wo, WT2, WoT, bpE);
    k_frontend<<<dim3(B_ * L_ / 32), dim3(256), 0, stream>>>(
        x, WT2, bpE, bs, dt_log, zT, cT);
    k_scan<<<dim3(B_ * N_), dim3(64), 0, stream>>>(zT, cT, A_log, dt_log, yH);
    k_out<<<dim3(B_ * L_ / 64, D_ / 128), dim3(256), 0, stream>>>(yH, WoT, bo, out);
}

// Round 3
// 198.068 us; speedup vs baseline: 1.3108x; 1.2203x over previous
//
#include <hip/hip_runtime.h>

#define B_ 4
#define L_ 4096
#define D_ 1024
#define N_ 64

typedef _Float16 f16;
typedef __attribute__((ext_vector_type(8))) _Float16 half8;
typedef __attribute__((ext_vector_type(4))) float f32x4;

__device__ __forceinline__ float softplus_f(float x) {
    return fmaxf(x, 0.0f) + log1pf(__expf(-fabsf(x)));
}

__device__ __forceinline__ float tanh_f(float x) {
    float xc = fminf(fmaxf(x, -15.0f), 15.0f);
    float e = __expf(2.0f * xc);
    return (e - 1.0f) / (e + 1.0f);
}

// ---------------------------------------------------------------------------
// Prep: WT [192][1024] fp16 (rows 0-127 = Wp cols, 128-191 = Ws cols);
// WoT [1024][64] fp16 (WoT[d][n] = Wo[n][d]).   (round-0 proven version)
// ---------------------------------------------------------------------------
__global__ __launch_bounds__(256) void k_prepw(
    const float* __restrict__ Wp, const float* __restrict__ Ws,
    const float* __restrict__ Wo, f16* __restrict__ WT, f16* __restrict__ WoT)
{
    int gid = blockIdx.x * 256 + threadIdx.x;
    if (gid < 24576) {
        int r = gid >> 7, kg = gid & 127;
        const float* src; int ncol, c;
        if (r < 128) { src = Wp; ncol = 128; c = r; }
        else         { src = Ws; ncol = 64;  c = r - 128; }
        f16 h[8];
        #pragma unroll
        for (int j = 0; j < 8; j++)
            h[j] = (f16)src[(size_t)(kg * 8 + j) * ncol + c];
        *(uint4*)&WT[(size_t)r * 1024 + kg * 8] = *(uint4*)h;
    } else {
        int g2 = gid - 24576;                 // < 8192
        int d = g2 >> 3, ng = g2 & 7;
        f16 h[8];
        #pragma unroll
        for (int j = 0; j < 8; j++)
            h[j] = (f16)Wo[(size_t)(ng * 8 + j) * D_ + d];
        *(uint4*)&WoT[(size_t)d * 64 + ng * 8] = *(uint4*)h;
    }
}

// ---------------------------------------------------------------------------
// Fused frontend v4: 256 thr / 4 waves, 16 tokens/block -> 1024 blocks
// (4 blocks/CU, 2x round-0 occupancy).  Conv computed ONCE per chunk into
// ch[] LDS (no per-wave redundancy, no in-loop conv_w loads); conv weights
// staged to LDS once.  Wave w owns cols w*48..+47 (3 m-frags) x 16 tokens
// (1 n-frag).  Epilogue sE aliases main-loop LDS (cwS dead after loop).
// ---------------------------------------------------------------------------
__global__ __launch_bounds__(256) void k_frontend(
    const float* __restrict__ x, const float* __restrict__ conv_w,
    const float* __restrict__ conv_b, const f16* __restrict__ WT,
    const float* __restrict__ bp, const float* __restrict__ bs,
    const float* __restrict__ dt_log,
    f16* __restrict__ zT, f16* __restrict__ cT)
{
    // layout: xh [20][72] f16 @0 (2880B); ch [16][72] f16 @2880 (2304B);
    // cwS [5][1024] f32 @5184 (20480B); total 25664B.
    // sE [3][16][68] f32 (13056B) aliases @0 in the epilogue.
    __shared__ __align__(16) char smem[25664];
    f16*   xh  = (f16*)smem;
    f16*   ch  = (f16*)(smem + 2880);
    float* cwS = (float*)(smem + 5184);
    float* sE  = (float*)smem;

    const int tid = threadIdx.x;
    const int w = tid >> 6, lane = tid & 63;
    const int r = lane & 15, q = lane >> 4;
    const int T0 = blockIdx.x * 16;
    const int bb = T0 >> 12;
    const int l0 = T0 & (L_ - 1);
    const int cw0 = w * 48;

    f32x4 acc[3] = {};
    float4 rA, rB;

    // stage conv weights + bias into LDS (once; visible after barrier (a))
    #pragma unroll
    for (int i = 0; i < 5; i++) {
        int idx = tid + 256 * i;
        float4 v = (idx < 1024) ? ((const float4*)conv_w)[idx]
                                : ((const float4*)conv_b)[idx - 1024];
        ((float4*)cwS)[idx] = v;
    }

    // staging: 20 rows x 16 float4 = 320 slots; tid<64 takes a second slot
    #define LDX(c0)                                                          \
        {                                                                    \
            {                                                                \
                int row = tid >> 4, g = tid & 15;                            \
                int l = l0 + row - 4;                                        \
                float4 v = make_float4(0.f, 0.f, 0.f, 0.f);                  \
                if (l >= 0)                                                  \
                    v = *(const float4*)&x[((size_t)(bb * L_ + l)) * D_      \
                                           + (c0) + g * 4];                  \
                rA = v;                                                      \
            }                                                                \
            if (tid < 64) {                                                  \
                int row = 16 + (tid >> 4), g = tid & 15;                     \
                int l = l0 + row - 4; /* >= 12, always valid */              \
                rB = *(const float4*)&x[((size_t)(bb * L_ + l)) * D_         \
                                        + (c0) + g * 4];                     \
            }                                                                \
        }

    LDX(0);
    for (int c = 0; c < 16; c++) {
        __syncthreads();   // (a) prev MFMA/conv reads done; cwS visible (c==0)
        {
            int row = tid >> 4, g = tid & 15;
            f16 h[4] = {(f16)rA.x, (f16)rA.y, (f16)rA.z, (f16)rA.w};
            *(uint2*)&xh[row * 72 + g * 4] = *(uint2*)h;
            if (tid < 64) {
                int row2 = 16 + (tid >> 4);
                f16 h2[4] = {(f16)rB.x, (f16)rB.y, (f16)rB.z, (f16)rB.w};
                *(uint2*)&xh[row2 * 72 + g * 4] = *(uint2*)h2;
            }
        }
        __syncthreads();   // (b) xh ready
        if (c < 15) LDX((c + 1) * 64);

        const int k0 = c * 64;

        // issue A-frag loads early (L2-resident WT, overlap with conv)
        half8 af[2][3];
        #pragma unroll
        for (int ks = 0; ks < 2; ks++)
            #pragma unroll
            for (int mf = 0; mf < 3; mf++)
                af[ks][mf] = *(const half8*)&WT[
                    (size_t)(cw0 + mf * 16 + r) * 1024 + k0 + ks * 32 + q * 8];

        // conv: each thread computes 4 elems of the 16x64 chunk (once!)
        {
            const int row = tid >> 4;          // 0..15 (token t = l0+row)
            const int d4 = (tid & 15) * 4;
            const int dg = k0 + d4;
            f32x4 w0 = *(const f32x4*)&cwS[dg];
            f32x4 w1 = *(const f32x4*)&cwS[1024 + dg];
            f32x4 w2 = *(const f32x4*)&cwS[2048 + dg];
            f32x4 w3 = *(const f32x4*)&cwS[3072 + dg];
            f32x4 cb = *(const f32x4*)&cwS[4096 + dg];
            f16 x0[4], x1[4], x2[4], x3[4], ho[4];
            *(uint2*)x0 = *(const uint2*)&xh[(row + 1) * 72 + d4]; // t-3 (k=0)
            *(uint2*)x1 = *(const uint2*)&xh[(row + 2) * 72 + d4]; // t-2 (k=1)
            *(uint2*)x2 = *(const uint2*)&xh[(row + 3) * 72 + d4]; // t-1 (k=2)
            *(uint2*)x3 = *(const uint2*)&xh[(row + 4) * 72 + d4]; // t   (k=3)
            #pragma unroll
            for (int j = 0; j < 4; j++) {
                float s = cb[j];
                s = fmaf(w0[j], (float)x0[j], s);
                s = fmaf(w1[j], (float)x1[j], s);
                s = fmaf(w2[j], (float)x2[j], s);
                s = fmaf(w3[j], (float)x3[j], s);
                ho[j] = (f16)s;
            }
            *(uint2*)&ch[row * 72 + d4] = *(uint2*)ho;
        }
        __syncthreads();   // (c) ch ready

        const bool needC = (cw0 < 128);          // w 0,1,2
        const bool needR = (cw0 + 32 >= 128);    // w 2,3
        #pragma unroll
        for (int ks = 0; ks < 2; ks++) {
            const int kl = ks * 32 + q * 8;
            half8 bc = {}, br = {};
            if (needC) bc = *(const half8*)&ch[r * 72 + kl];
            if (needR) br = *(const half8*)&xh[(r + 4) * 72 + kl];
            #pragma unroll
            for (int mf = 0; mf < 3; mf++) {
                const bool useConv = (cw0 + mf * 16) < 128;
                acc[mf] = __builtin_amdgcn_mfma_f32_16x16x32_f16(
                    af[ks][mf], useConv ? bc : br, acc[mf], 0, 0, 0);
            }
        }
    }

    // --- epilogue: bias + activation -> sE (aliases xh/ch/cwS) ---
    float* sB = sE;
    float* sC = sE + 16 * 68;
    float* sU = sE + 2 * 16 * 68;
    __syncthreads();   // all LDS reads of xh/ch done before overwrite
    #pragma unroll
    for (int mf = 0; mf < 3; mf++) {
        const int cb4 = cw0 + mf * 16 + q * 4;
        const int seg = cb4 >> 6;          // 0=Bt 1=Ct 2=u (frag-uniform)
        const int cl = cb4 & 63;
        const float4 bb4 = (seg == 2) ? *(const float4*)&bs[cl]
                                      : *(const float4*)&bp[cb4];
        float* dst = (seg == 0) ? sB : (seg == 1 ? sC : sU);
        const int t = r;
        float v0 = acc[mf][0] + bb4.x;
        float v1 = acc[mf][1] + bb4.y;
        float v2 = acc[mf][2] + bb4.z;
        float v3 = acc[mf][3] + bb4.w;
        if (seg == 0) {
            v0 = softplus_f(v0); v1 = softplus_f(v1);
            v2 = softplus_f(v2); v3 = softplus_f(v3);
        } else if (seg == 1) {
            v0 = tanh_f(v0); v1 = tanh_f(v1);
            v2 = tanh_f(v2); v3 = tanh_f(v3);
        }
        float4 vv = {v0, v1, v2, v3};
        *(float4*)&dst[t * 68 + cl] = vv;
    }
    __syncthreads();

    // --- fused combine: z = dt[n]*Bt*u, store zT/cT n-major ---
    {
        const int n = tid >> 2, tg = tid & 3;
        const float dtv = softplus_f(dt_log[n]);
        f16 hz[4], hc[4];
        #pragma unroll
        for (int j = 0; j < 4; j++) {
            const int t = tg * 4 + j;
            hz[j] = (f16)(dtv * sB[t * 68 + n] * sU[t * 68 + n]);
            hc[j] = (f16)sC[t * 68 + n];
        }
        size_t o = ((size_t)(bb * N_ + n)) * L_ + l0 + tg * 4;
        *(uint2*)&zT[o] = *(uint2*)hz;
        *(uint2*)&cT[o] = *(uint2*)hc;
    }
    #undef LDX
}

// ---------------------------------------------------------------------------
// Scan: one wave per (b,n) chain; exact affine chunk-stitched scan.
// ---------------------------------------------------------------------------
__global__ __launch_bounds__(64) void k_scan(
    const f16* __restrict__ zT, const f16* __restrict__ cT,
    const float* __restrict__ A_log, const float* __restrict__ dt_log,
    f16* __restrict__ yH)
{
    __shared__ float zs[L_];
    __shared__ float cs[L_];
    const int bn = blockIdx.x;
    const int n = bn & (N_ - 1);
    const int lane = threadIdx.x;
    const f16* zp = zT + (size_t)bn * L_;
    const f16* cp = cT + (size_t)bn * L_;

    for (int it = 0; it < 8; it++) {
        int i = lane * 8 + it * 512;
        uint4 rz = *(const uint4*)(zp + i);
        uint4 rc = *(const uint4*)(cp + i);
        const f16* hz = (const f16*)&rz;
        const f16* hc = (const f16*)&rc;
        #pragma unroll
        for (int k = 0; k < 8; k++) {
            zs[i + k] = (float)hz[k];
            cs[i + k] = (float)hc[k];
        }
    }
    __syncthreads();

    float dtv = softplus_f(dt_log[n]);
    float Av = -softplus_f(A_log[n]);
    float dec = fmaf(dtv, Av, 1.0f);

    float s = 0.0f;
    const int base = lane * 64;
    #pragma unroll
    for (int j = 0; j < 64; j++) s = fmaf(dec, s, zs[base + j]);

    float d2 = dec * dec, d4 = d2 * d2, d8 = d4 * d4;
    float d16 = d8 * d8, d32 = d16 * d16, d64 = d32 * d32;

    float Ag = d64, Bg = s;
    #pragma unroll
    for (int off = 1; off < 64; off <<= 1) {
        float Ap = __shfl_up(Ag, off);
        float Bp = __shfl_up(Bg, off);
        if (lane >= off) { Bg = fmaf(Ag, Bp, Bg); Ag *= Ap; }
    }
    float carry = __shfl_up(Bg, 1);
    if (lane == 0) carry = 0.0f;

    float st = carry;
    #pragma unroll
    for (int j = 0; j < 64; j++) {
        st = fmaf(dec, st, zs[base + j]);
        zs[base + j] = cs[base + j] * st;
    }
    __syncthreads();
    f16* yp = yH + (size_t)bn * L_;
    for (int i = lane * 8; i < L_; i += 512) {
        f16 h[8];
        #pragma unroll
        for (int k = 0; k < 8; k++) h[k] = (f16)zs[i + k];
        *(uint4*)&yp[i] = *(uint4*)h;
    }
}

// ---------------------------------------------------------------------------
// Out GEMM: out[t][d] = y[t][:] @ Wo[:,d] + bo.  A = WoT (m=d), B = y (n=tok)
// -> D rows are d -> float4 coalesced stores.  Block 256 thr: 64 tok x 128 d,
// wave = 32 d x 64 tok.  Grid (256, 8) = 2048 blocks = 8/CU.
// ---------------------------------------------------------------------------
__global__ __launch_bounds__(256) void k_out(
    const f16* __restrict__ yH, const f16* __restrict__ WoT,
    const float* __restrict__ bo, float* __restrict__ out)
{
    __shared__ __align__(16) f16 ys[64 * 72];
    const int tid = threadIdx.x;
    const int w = tid >> 6, lane = tid & 63;
    const int r = lane & 15, q = lane >> 4;
    const int T0 = blockIdx.x * 64;
    const int bb = T0 >> 12, l0 = T0 & (L_ - 1);
    const int dw = blockIdx.y * 128 + w * 32;

    // stage y transpose: [n-major global] -> ys[t][n]
    {
        const int n = tid & 63, tg = tid >> 6;
        #pragma unroll
        for (int h2 = 0; h2 < 2; h2++) {
            uint4 v = *(const uint4*)&yH[((size_t)(bb * N_ + n)) * L_ + l0 + tg * 16 + h2 * 8];
            const f16* hh = (const f16*)&v;
            #pragma unroll
            for (int j = 0; j < 8; j++)
                ys[(tg * 16 + h2 * 8 + j) * 72 + n] = hh[j];
        }
    }
    __syncthreads();

    f32x4 acc[2][4] = {};
    #pragma unroll
    for (int ks = 0; ks < 2; ks++) {
        const int kk = ks * 32 + q * 8;
        half8 af[2];
        #pragma unroll
        for (int mf = 0; mf < 2; mf++)
            af[mf] = *(const half8*)&WoT[(size_t)(dw + mf * 16 + r) * 64 + kk];
        #pragma unroll
        for (int nf = 0; nf < 4; nf++) {
            half8 bf = *(const half8*)&ys[(nf * 16 + r) * 72 + kk];
            #pragma unroll
            for (int mf = 0; mf < 2; mf++)
                acc[mf][nf] = __builtin_amdgcn_mfma_f32_16x16x32_f16(
                    af[mf], bf, acc[mf][nf], 0, 0, 0);
        }
    }

    #pragma unroll
    for (int mf = 0; mf < 2; mf++) {
        const int d = dw + mf * 16 + q * 4;
        const float4 bb4 = *(const float4*)&bo[d];
        #pragma unroll
        for (int nf = 0; nf < 4; nf++) {
            const int t = T0 + nf * 16 + r;
            float4 o = {acc[mf][nf][0] + bb4.x, acc[mf][nf][1] + bb4.y,
                        acc[mf][nf][2] + bb4.z, acc[mf][nf][3] + bb4.w};
            *(float4*)&out[(size_t)t * D_ + d] = o;
        }
    }
}

// ---------------------------------------------------------------------------
extern "C" void kernel_launch(void* const* d_in, const int* in_sizes, int n_in,
                              void* d_out, int out_size, void* d_ws, size_t ws_size,
                              hipStream_t stream) {
    const float* x      = (const float*)d_in[0];
    const float* conv_w = (const float*)d_in[1];
    const float* conv_b = (const float*)d_in[2];
    const float* Wp     = (const float*)d_in[3];
    const float* bp     = (const float*)d_in[4];
    const float* Ws     = (const float*)d_in[5];
    const float* bs     = (const float*)d_in[6];
    const float* A_log  = (const float*)d_in[7];
    const float* dt_log = (const float*)d_in[8];
    const float* Wo     = (const float*)d_in[9];
    const float* bo     = (const float*)d_in[10];
    float* out = (float*)d_out;

    char* wsp = (char*)d_ws;
    f16* WT  = (f16*)wsp;                     // 384 KB
    f16* WoT = (f16*)(wsp + 393216);          // 128 KB
    f16* zT  = (f16*)(wsp + 524288);          // 2 MB [B,N,L]
    f16* cT  = (f16*)(wsp + 2621440);         // 2 MB
    f16* yH  = (f16*)(wsp + 4718592);         // 2 MB

    k_prepw<<<dim3(128), dim3(256), 0, stream>>>(Wp, Ws, Wo, WT, WoT);
    k_frontend<<<dim3(B_ * L_ / 16), dim3(256), 0, stream>>>(
        x, conv_w, conv_b, WT, bp, bs, dt_log, zT, cT);
    k_scan<<<dim3(B_ * N_), dim3(64), 0, stream>>>(zT, cT, A_log, dt_log, yH);
    k_out<<<dim3(B_ * L_ / 64, D_ / 128), dim3(256), 0, stream>>>(yH, WoT, bo, out);
}